// Round 12
// baseline (3927.371 us; speedup 1.0000x reference)
//
#include <hip/hip_runtime.h>

#define NXg 512
#define NYg 512
#define NNg (NXg*NYg)
#define TPB 512
#define NBT 128
#define ROWS 4
#define NSTEPS 8
#define CGIT 10
#define DTf (1.0f/64.0f)
#define H2I 256.0f

// ws float layout — cross-block traffic via relaxed AGENT (sc1) atomics only.
// NO __threadfence anywhere. Only BOUNDARY rows (2 of 4 per block) published.
//  [b*16], b<128        arrival flags (int)
//  [2048 .. 6144)       parts[2 parity][16 metric][128 block]
//  [8192 ..)            R[4ch][NNg] | P[2 par][4 ch][NNg]  (boundary rows only used)
#define PARTS_OFF   2048
#define CTRL_FLOATS 8192
#define R_OFF(c)      (CTRL_FLOATS + (c)*NNg)
#define P_OFF(par,c)  (CTRL_FLOATS + 4*NNg + ((par)*4+(c))*NNg)

__device__ __forceinline__ int ld_flag(int* p){
  return __hip_atomic_load(p, __ATOMIC_RELAXED, __HIP_MEMORY_SCOPE_AGENT);
}
__device__ __forceinline__ void st_flag(int* p, int v){
  __hip_atomic_store(p, v, __ATOMIC_RELAXED, __HIP_MEMORY_SCOPE_AGENT);
}
__device__ __forceinline__ float ldg1(float* p){
  return __hip_atomic_load(p, __ATOMIC_RELAXED, __HIP_MEMORY_SCOPE_AGENT);
}
__device__ __forceinline__ void stg1(float* p, float v){
  __hip_atomic_store(p, v, __ATOMIC_RELAXED, __HIP_MEMORY_SCOPE_AGENT);
}
// 8B packed relaxed agent atomics (halve the atomic-op count)
union F2U { unsigned long long u; float2 f; };
__device__ __forceinline__ float2 ldg2(float* p){
  F2U t; t.u = __hip_atomic_load((unsigned long long*)p, __ATOMIC_RELAXED, __HIP_MEMORY_SCOPE_AGENT);
  return t.f;
}
__device__ __forceinline__ void stg2(float* p, float2 v){
  F2U t; t.f = v;
  __hip_atomic_store((unsigned long long*)p, t.u, __ATOMIC_RELAXED, __HIP_MEMORY_SCOPE_AGENT);
}

// Fence-free all-to-all barrier: vmcnt(0) drains sc1 stores, flag store,
// wave 0 polls all 128 flags directly (2 per lane). Relaxed spins only.
__device__ __forceinline__ void gsync(int* wsi, int bid, int tid, int tgt){
  asm volatile("s_waitcnt vmcnt(0)" ::: "memory");
  __syncthreads();
  if (tid==0) st_flag(&wsi[bid*16], tgt);
  if (tid<64){
    int ok=0;
    while(!ok){
      int m = (ld_flag(&wsi[(2*tid)*16])   >= tgt) &
              (ld_flag(&wsi[(2*tid+1)*16]) >= tgt);
      ok=__all(m);
      if(!ok) __builtin_amdgcn_s_sleep(1);
    }
  }
  __syncthreads();
}

__device__ __forceinline__ void mlp_all(const float* sW, const float* vv, float* o){
  float h1[16];
  #pragma unroll
  for (int h=0;h<16;++h)
    h1[h] = tanhf(vv[0]*sW[h]+vv[1]*sW[16+h]+vv[2]*sW[32+h]+vv[3]*sW[48+h]);
  o[0]=o[1]=o[2]=o[3]=0.f;
  #pragma unroll
  for (int j=0;j<16;++j){
    float s=0.f;
    #pragma unroll
    for (int h=0;h<16;++h) s += h1[h]*sW[64+16*h+j];
    const float t = tanhf(s);
    o[0]+=t*sW[320+4*j+0]; o[1]+=t*sW[320+4*j+1];
    o[2]+=t*sW[320+4*j+2]; o[3]+=t*sW[320+4*j+3];
  }
}

__global__ void __launch_bounds__(TPB, 2)
drk(const float* __restrict__ U0, const float* __restrict__ scale,
    const float* __restrict__ K1, const float* __restrict__ K2,
    const float* __restrict__ K3, float* __restrict__ out,
    float* __restrict__ ws)
{
  __shared__ float sW[384];
  __shared__ float sP[ROWS][4][NXg];  // pn tile, 32 KB
  __shared__ float wRed[8][8];
  __shared__ float sRed[12];

  const int tid=threadIdx.x, bid=blockIdx.x;
  const int r    = tid>>7;          // row in block: 0..3
  const int ci   = tid&127;
  const int c4   = ci*4;            // 4 consecutive cols per thread
  const int lane = tid&63;
  const int wv   = tid>>6;          // wave 0..7
  const int grow = bid*ROWS + r;
  const int cell0= grow*NXg + c4;
  const bool topB = (r==0), botB = (r==ROWS-1);
  const bool hasHalo = (topB && bid>0) || (botB && bid<NBT-1);
  const int hrow = topB ? (grow-1) : (grow+1);

  if (tid < 384){
    float w;
    if (tid < 64)       w = K1[tid];
    else if (tid < 320) w = K2[tid-64];
    else                w = K3[tid-320];
    sW[tid]=w;
  }
  __syncthreads();

  int* wsi = (int*)ws;
  float gam[4];
  #pragma unroll
  for (int c=0;c<4;++c) gam[c] = 1.0f/(scale[c]*DTf);

  float xnew[4][4];
  #pragma unroll
  for (int k=0;k<4;++k){
    const float4 u = ((const float4*)U0)[cell0+k];
    xnew[k][0]=u.x; xnew[k][1]=u.y; xnew[k][2]=u.z; xnew[k][3]=u.w;
  }

  for (int step=0; step<NSTEPS; ++step){
    float rr[4][4], xx[4][4], pold[4][4];
    float alpha[4], beta[4], rs[4], bb[4];
    #pragma unroll
    for (int c=0;c<4;++c){
      bb[c]=0.f; beta[c]=0.f;
      #pragma unroll
      for (int k=0;k<4;++k){
        rr[k][c] = gam[c]*xnew[k][c];
        bb[c]   += rr[k][c]*rr[k][c];
        xx[k][c]=0.f; pold[k][c]=0.f;
      }
    }

    for (int it=0; it<CGIT; ++it){
      const int g = step*CGIT + it;
      const int par = g&1;
      float* parts = ws + PARTS_OFF + par*2048;

      // ---- phase A: pn = r + beta*p_old; tile; publish boundary rows ----
      float pn[4][4], Ap[4][4];
      #pragma unroll
      for (int k=0;k<4;++k)
      #pragma unroll
      for (int c=0;c<4;++c){
        pn[k][c] = rr[k][c] + beta[c]*pold[k][c];
        sP[r][c][c4+k] = pn[k][c];
      }
      if ((topB||botB) && it<CGIT-1){
        #pragma unroll
        for (int c=0;c<4;++c){
          stg2(ws + P_OFF(par,c) + grow*NXg + c4,   make_float2(pn[0][c],pn[1][c]));
          stg2(ws + P_OFF(par,c) + grow*NXg + c4+2, make_float2(pn[2][c],pn[3][c]));
        }
      }

      // halo pn = R_halo + beta*P_halo(prev parity); synced >=1 gsync ago
      float pnh[4][4];
      #pragma unroll
      for (int k=0;k<4;++k)
      #pragma unroll
      for (int c=0;c<4;++c) pnh[k][c]=0.f;
      if (hasHalo){
        if (step==0 && it==0){
          #pragma unroll
          for (int k=0;k<4;++k){
            const float4 h = ((const float4*)U0)[hrow*NXg + c4 + k];
            pnh[k][0]=gam[0]*h.x; pnh[k][1]=gam[1]*h.y;
            pnh[k][2]=gam[2]*h.z; pnh[k][3]=gam[3]*h.w;
          }
        } else {
          #pragma unroll
          for (int c=0;c<4;++c){
            const float2 a  = ldg2(ws + R_OFF(c) + hrow*NXg + c4);
            const float2 b2 = ldg2(ws + R_OFF(c) + hrow*NXg + c4+2);
            const float2 pa = ldg2(ws + P_OFF(par^1,c) + hrow*NXg + c4);
            const float2 pb = ldg2(ws + P_OFF(par^1,c) + hrow*NXg + c4+2);
            pnh[0][c]=a.x +beta[c]*pa.x; pnh[1][c]=a.y +beta[c]*pa.y;
            pnh[2][c]=b2.x+beta[c]*pb.x; pnh[3][c]=b2.y+beta[c]*pb.y;
          }
        }
      }
      __syncthreads();   // sP tile complete

      // ---- stencil + pAp partials ----
      float pap[4]={0,0,0,0};
      #pragma unroll
      for (int c=0;c<4;++c)
      #pragma unroll
      for (int k=0;k<4;++k){
        const int col = c4+k;
        const float u = pn[k][c];
        float s = 0.f;
        if (r>0)        s += u - sP[r-1][c][col];
        else if (grow>0)     s += u - pnh[k][c];
        if (r<ROWS-1)   s += u - sP[r+1][c][col];
        else if (grow<NYg-1) s += u - pnh[k][c];
        if (k>0)        s += u - pn[k-1][c];
        else if (col>0)      s += u - sP[r][c][col-1];
        if (k<3)        s += u - pn[k+1][c];
        else if (col<NXg-1)  s += u - sP[r][c][col+1];
        const float ap = s*H2I + gam[c]*u;
        Ap[k][c] = ap;
        pap[c]  += u*ap;
      }

      // block-reduce 8 metrics {pAp[4], bb[4]}
      {
        float m8[8];
        #pragma unroll
        for (int c=0;c<4;++c){ m8[c]=pap[c]; m8[4+c]=bb[c]; }
        #pragma unroll
        for (int m=0;m<8;++m){
          float v=m8[m];
          #pragma unroll
          for (int off=32; off; off>>=1) v += __shfl_xor(v, off);
          m8[m]=v;
        }
        if (lane==0){
          #pragma unroll
          for (int m=0;m<8;++m) wRed[wv][m]=m8[m];
        }
        __syncthreads();
        if (tid<8){
          float s=0.f;
          #pragma unroll
          for (int w=0;w<8;++w) s += wRed[w][tid];
          stg1(parts + tid*128 + bid, s);
        }
      }
      gsync(wsi, bid, tid, 2*g+1);

      // all-to-all: wave wv sums metric wv over 128 blocks (2 per lane)
      {
        float s = ldg1(parts + wv*128 + lane*2) + ldg1(parts + wv*128 + lane*2+1);
        #pragma unroll
        for (int off=32; off; off>>=1) s += __shfl_xor(s, off);
        if (lane==0) sRed[wv]=s;
      }
      __syncthreads();
      #pragma unroll
      for (int c=0;c<4;++c){
        if (it==0) rs[c] = sRed[4+c];
        alpha[c] = rs[c]/sRed[c];
      }
      #pragma unroll
      for (int k=0;k<4;++k)
      #pragma unroll
      for (int c=0;c<4;++c){
        xx[k][c] += alpha[c]*pn[k][c];
        rr[k][c] -= alpha[c]*Ap[k][c];
      }

      if (it < CGIT-1){
        // ---- phase B: publish boundary r; DIRECT Σr² reduce ----
        if (topB||botB){
          #pragma unroll
          for (int c=0;c<4;++c){
            stg2(ws + R_OFF(c) + grow*NXg + c4,   make_float2(rr[0][c],rr[1][c]));
            stg2(ws + R_OFF(c) + grow*NXg + c4+2, make_float2(rr[2][c],rr[3][c]));
          }
        }
        {
          float m4[4];
          #pragma unroll
          for (int c=0;c<4;++c)
            m4[c] = rr[0][c]*rr[0][c]+rr[1][c]*rr[1][c]
                  + rr[2][c]*rr[2][c]+rr[3][c]*rr[3][c];
          #pragma unroll
          for (int m=0;m<4;++m){
            float v=m4[m];
            #pragma unroll
            for (int off=32; off; off>>=1) v += __shfl_xor(v, off);
            m4[m]=v;
          }
          if (lane==0){
            #pragma unroll
            for (int m=0;m<4;++m) wRed[wv][m]=m4[m];
          }
          __syncthreads();
          if (tid<4){
            float s=0.f;
            #pragma unroll
            for (int w=0;w<8;++w) s += wRed[w][tid];
            stg1(parts + (8+tid)*128 + bid, s);
          }
        }
        gsync(wsi, bid, tid, 2*g+2);
        if (wv<4){
          float s = ldg1(parts + (8+wv)*128 + lane*2) + ldg1(parts + (8+wv)*128 + lane*2+1);
          #pragma unroll
          for (int off=32; off; off>>=1) s += __shfl_xor(s, off);
          if (lane==0) sRed[8+wv]=s;
        }
        __syncthreads();
        #pragma unroll
        for (int c=0;c<4;++c){
          beta[c] = sRed[8+c]/rs[c];
          rs[c]   = sRed[8+c];
        }
        #pragma unroll
        for (int k=0;k<4;++k)
        #pragma unroll
        for (int c=0;c<4;++c) pold[k][c]=pn[k][c];
      } else {
        // ---- last iter: reaction (block-local), publish next-b boundary ----
        #pragma unroll
        for (int k=0;k<4;++k){
          float vv[4] = {xx[k][0], xx[k][1], xx[k][2], xx[k][3]};
          float o[4];
          mlp_all(sW, vv, o);
          #pragma unroll
          for (int c=0;c<4;++c) xnew[k][c] = xx[k][c] + DTf*tanhf(o[c]);
        }
        if (step < NSTEPS-1){
          if (topB||botB){
            #pragma unroll
            for (int c=0;c<4;++c){
              stg2(ws + R_OFF(c) + grow*NXg + c4,
                   make_float2(gam[c]*xnew[0][c], gam[c]*xnew[1][c]));
              stg2(ws + R_OFF(c) + grow*NXg + c4+2,
                   make_float2(gam[c]*xnew[2][c], gam[c]*xnew[3][c]));
            }
          }
          gsync(wsi, bid, tid, 2*g+2);   // folded step-boundary sync
        } else {
          #pragma unroll
          for (int k=0;k<4;++k)
            ((float4*)out)[cell0+k] =
              make_float4(xnew[k][0],xnew[k][1],xnew[k][2],xnew[k][3]);
        }
      }
    }
  }
}

// diagnostic: runs ONLY if ws is too small — absmax ≈ 54321 signals that.
__global__ void diag_ws(float* out){ out[0] = 54321.0f; }

extern "C" void kernel_launch(void* const* d_in, const int* in_sizes, int n_in,
                              void* d_out, int out_size, void* d_ws, size_t ws_size,
                              hipStream_t stream) {
  const float* U0    = (const float*)d_in[0];
  const float* scale = (const float*)d_in[1];
  const float* K1    = (const float*)d_in[2];
  const float* K2    = (const float*)d_in[3];
  const float* K3    = (const float*)d_in[4];
  float* out = (float*)d_out;
  float* ws  = (float*)d_ws;

  const size_t need = (size_t)(CTRL_FLOATS + 12*NNg) * sizeof(float);
  if (ws_size < need) {
    hipLaunchKernelGGL(diag_ws, dim3(1), dim3(1), 0, stream, out);
    return;
  }
  // zero flags + parts (harness poisons ws with 0xAA)
  hipMemsetAsync(ws, 0, CTRL_FLOATS*sizeof(float), stream);
  hipLaunchKernelGGL(drk, dim3(NBT), dim3(TPB), 0, stream,
                     U0, scale, K1, K2, K3, out, ws);
}

// Round 13
// 2175.130 us; speedup vs baseline: 1.8056x; 1.8056x over previous
//
#include <hip/hip_runtime.h>

#define NXg 512
#define NYg 512
#define NNg (NXg*NYg)
#define TPB 512
#define NBT 256
#define NSTEPS 8
#define CGIT 10
#define DTf (1.0f/64.0f)
#define H2I 256.0f

// ws float layout — cross-block traffic via relaxed AGENT (sc1) atomics only.
// NO __threadfence anywhere. ONLY the r plane crosses blocks (pn halo is a
// register mirror: pn_h(it) = r_h(it) + beta*pn_h(it-1), reader-maintained).
//  [b*16], b<256        arrival flags (int)
//  [4096 + l*16], l<64  release lines (int)
//  [8192 .. 16384)      parts[2 parity][16 metric][256 block]
//  [16384 ..)           R[4ch][NNg]
#define REL_OFF     4096
#define PARTS_OFF   8192
#define CTRL_FLOATS 16384
#define R_OFF(c)    (CTRL_FLOATS + (c)*NNg)

__device__ __forceinline__ int ld_flag(int* p){
  return __hip_atomic_load(p, __ATOMIC_RELAXED, __HIP_MEMORY_SCOPE_AGENT);
}
__device__ __forceinline__ void st_flag(int* p, int v){
  __hip_atomic_store(p, v, __ATOMIC_RELAXED, __HIP_MEMORY_SCOPE_AGENT);
}
__device__ __forceinline__ float ldg1(float* p){
  return __hip_atomic_load(p, __ATOMIC_RELAXED, __HIP_MEMORY_SCOPE_AGENT);
}
__device__ __forceinline__ void stg1(float* p, float v){
  __hip_atomic_store(p, v, __ATOMIC_RELAXED, __HIP_MEMORY_SCOPE_AGENT);
}
// 8B packed relaxed agent atomics (halve the fabric op count)
union F2U { unsigned long long u; float2 f; };
__device__ __forceinline__ float2 ldg2(float* p){
  F2U t; t.u = __hip_atomic_load((unsigned long long*)p, __ATOMIC_RELAXED, __HIP_MEMORY_SCOPE_AGENT);
  return t.f;
}
__device__ __forceinline__ void stg2(float* p, float2 v){
  F2U t; t.f = v;
  __hip_atomic_store((unsigned long long*)p, t.u, __ATOMIC_RELAXED, __HIP_MEMORY_SCOPE_AGENT);
}

// Fence-free barrier (r11-proven): vmcnt(0) drains this wave's sc1 ops,
// flag store; block 0 polls 256 flags, broadcasts via 64 release lines.
__device__ __forceinline__ void gsync(int* wsi, int bid, int tid, int tgt){
  asm volatile("s_waitcnt vmcnt(0)" ::: "memory");
  __syncthreads();
  if (tid==0) st_flag(&wsi[bid*16], tgt);
  if (bid==0 && tid<64){
    int ok=0;
    while(!ok){
      int m=1;
      #pragma unroll
      for (int j=0;j<4;++j) m &= (ld_flag(&wsi[(tid+64*j)*16]) >= tgt);
      ok=__all(m);
      if(!ok) __builtin_amdgcn_s_sleep(1);
    }
    st_flag(&wsi[REL_OFF + tid*16], tgt);
  }
  if (tid==0){
    int* rl = &wsi[REL_OFF + (bid&63)*16];
    while(ld_flag(rl) < tgt) __builtin_amdgcn_s_sleep(1);
  }
  __syncthreads();
}

__device__ __forceinline__ void mlp_all(const float* sW, const float* vv, float* o){
  float h1[16];
  #pragma unroll
  for (int h=0;h<16;++h)
    h1[h] = tanhf(vv[0]*sW[h]+vv[1]*sW[16+h]+vv[2]*sW[32+h]+vv[3]*sW[48+h]);
  o[0]=o[1]=o[2]=o[3]=0.f;
  #pragma unroll
  for (int j=0;j<16;++j){
    float s=0.f;
    #pragma unroll
    for (int h=0;h<16;++h) s += h1[h]*sW[64+16*h+j];
    const float t = tanhf(s);
    o[0]+=t*sW[320+4*j+0]; o[1]+=t*sW[320+4*j+1];
    o[2]+=t*sW[320+4*j+2]; o[3]+=t*sW[320+4*j+3];
  }
}

__global__ void __launch_bounds__(TPB)
drk(const float* __restrict__ U0, const float* __restrict__ scale,
    const float* __restrict__ K1, const float* __restrict__ K2,
    const float* __restrict__ K3, float* __restrict__ out,
    float* __restrict__ ws)
{
  __shared__ float sW[384];
  __shared__ float sP[2][4][NXg];   // pn tile, 16 KB
  __shared__ float wRed[8][8];
  __shared__ float sRed[12];

  const int tid=threadIdx.x, bid=blockIdx.x;
  const int r    = tid>>8;          // row in block: 0/1
  const int lane = tid&63;
  const int wv   = tid>>6;          // wave 0..7
  const int c2   = (tid&255)*2;     // column base (2 cells/thread)
  const int grow = bid*2 + r;
  const int cell0= grow*NXg + c2;
  const bool hUp = (r==0) && (grow>0);
  const bool hDn = (r==1) && (grow<NYg-1);
  const bool hasHalo = hUp || hDn;
  const int hrow = (r==0) ? (grow-1) : (grow+1);

  if (tid < 384){
    float w;
    if (tid < 64)       w = K1[tid];
    else if (tid < 320) w = K2[tid-64];
    else                w = K3[tid-320];
    sW[tid]=w;
  }
  __syncthreads();

  int* wsi = (int*)ws;
  float gam[4];
  #pragma unroll
  for (int c=0;c<4;++c) gam[c] = 1.0f/(scale[c]*DTf);

  float xnew[2][4];
  {
    const float4 u0 = ((const float4*)U0)[cell0];
    const float4 u1 = ((const float4*)U0)[cell0+1];
    xnew[0][0]=u0.x; xnew[0][1]=u0.y; xnew[0][2]=u0.z; xnew[0][3]=u0.w;
    xnew[1][0]=u1.x; xnew[1][1]=u1.y; xnew[1][2]=u1.z; xnew[1][3]=u1.w;
  }

  for (int step=0; step<NSTEPS; ++step){
    float rr[2][4], xx[2][4], pold[2][4], pnh[2][4];
    float alpha[4], beta[4], rs[4], bb[4];
    #pragma unroll
    for (int c=0;c<4;++c){
      bb[c]=0.f; beta[c]=0.f;
      #pragma unroll
      for (int k=0;k<2;++k){
        rr[k][c] = gam[c]*xnew[k][c];
        bb[c]   += rr[k][c]*rr[k][c];
        xx[k][c]=0.f; pold[k][c]=0.f; pnh[k][c]=0.f;
      }
    }

    for (int it=0; it<CGIT; ++it){
      const int g = step*CGIT + it;
      const int par = g&1;
      float* parts = ws + PARTS_OFF + par*4096;

      // ---- phase A: pn = r + beta*p_old; tile; pnh register mirror ----
      float pn[2][4], Ap[2][4];
      #pragma unroll
      for (int k=0;k<2;++k)
      #pragma unroll
      for (int c=0;c<4;++c){
        pn[k][c] = rr[k][c] + beta[c]*pold[k][c];
        sP[r][c][c2+k] = pn[k][c];
      }

      // pnh(it) = r_h(it) + beta*pnh(it-1); r_h from the published R plane
      // (phase B of it-1, synced at gsync(2(g-1)+2); step-boundary b folded).
      if (hasHalo){
        if (step==0 && it==0){
          const float4 h0 = ((const float4*)U0)[hrow*NXg + c2];
          const float4 h1 = ((const float4*)U0)[hrow*NXg + c2+1];
          pnh[0][0]=gam[0]*h0.x; pnh[0][1]=gam[1]*h0.y; pnh[0][2]=gam[2]*h0.z; pnh[0][3]=gam[3]*h0.w;
          pnh[1][0]=gam[0]*h1.x; pnh[1][1]=gam[1]*h1.y; pnh[1][2]=gam[2]*h1.z; pnh[1][3]=gam[3]*h1.w;
        } else {
          #pragma unroll
          for (int c=0;c<4;++c){
            const float2 h = ldg2(ws + R_OFF(c) + hrow*NXg + c2);
            pnh[0][c] = h.x + beta[c]*pnh[0][c];
            pnh[1][c] = h.y + beta[c]*pnh[1][c];
          }
        }
      }
      __syncthreads();   // sP tile complete

      // ---- stencil + pAp partials ----
      float pap[4]={0,0,0,0};
      #pragma unroll
      for (int c=0;c<4;++c)
      #pragma unroll
      for (int k=0;k<2;++k){
        const int col = c2+k;
        const float u = pn[k][c];
        float s = 0.f;
        if (r==1) s += u - sP[0][c][col]; else if (grow>0)     s += u - pnh[k][c];
        if (r==0) s += u - sP[1][c][col]; else if (grow<NYg-1) s += u - pnh[k][c];
        if (col > 0)     s += u - ((k==1) ? pn[0][c] : sP[r][c][col-1]);
        if (col < NXg-1) s += u - ((k==0) ? pn[1][c] : sP[r][c][col+1]);
        const float ap = s*H2I + gam[c]*u;
        Ap[k][c] = ap;
        pap[c]  += u*ap;
      }

      // block-reduce 8 metrics {pAp[4], bb[4]} -> parts
      {
        float m8[8];
        #pragma unroll
        for (int c=0;c<4;++c){ m8[c]=pap[c]; m8[4+c]=bb[c]; }
        #pragma unroll
        for (int m=0;m<8;++m){
          float v=m8[m];
          #pragma unroll
          for (int off=32; off; off>>=1) v += __shfl_xor(v, off);
          m8[m]=v;
        }
        if (lane==0){
          #pragma unroll
          for (int m=0;m<8;++m) wRed[wv][m]=m8[m];
        }
        __syncthreads();
        if (tid<8){
          float s=0.f;
          #pragma unroll
          for (int w=0;w<8;++w) s += wRed[w][tid];
          stg1(parts + tid*256 + bid, s);
        }
      }
      gsync(wsi, bid, tid, 2*g+1);

      // all-to-all read: wave wv sums metric wv over 256 blocks
      {
        float s=0.f;
        #pragma unroll
        for (int j=0;j<4;++j) s += ldg1(parts + wv*256 + lane*4+j);
        #pragma unroll
        for (int off=32; off; off>>=1) s += __shfl_xor(s, off);
        if (lane==0) sRed[wv]=s;
      }
      __syncthreads();
      #pragma unroll
      for (int c=0;c<4;++c){
        if (it==0) rs[c] = sRed[4+c];
        alpha[c] = rs[c]/sRed[c];
      }
      #pragma unroll
      for (int k=0;k<2;++k)
      #pragma unroll
      for (int c=0;c<4;++c){
        xx[k][c] += alpha[c]*pn[k][c];
        rr[k][c] -= alpha[c]*Ap[k][c];
      }

      if (it < CGIT-1){
        // ---- phase B: publish r (stg2, boundary rows = all rows here);
        //      DIRECT Σr² reduce (no recurrence) ----
        #pragma unroll
        for (int c=0;c<4;++c)
          stg2(ws + R_OFF(c) + grow*NXg + c2, make_float2(rr[0][c],rr[1][c]));
        {
          float m4[4];
          #pragma unroll
          for (int c=0;c<4;++c)
            m4[c] = rr[0][c]*rr[0][c] + rr[1][c]*rr[1][c];
          #pragma unroll
          for (int m=0;m<4;++m){
            float v=m4[m];
            #pragma unroll
            for (int off=32; off; off>>=1) v += __shfl_xor(v, off);
            m4[m]=v;
          }
          if (lane==0){
            #pragma unroll
            for (int m=0;m<4;++m) wRed[wv][m]=m4[m];
          }
          __syncthreads();
          if (tid<4){
            float s=0.f;
            #pragma unroll
            for (int w=0;w<8;++w) s += wRed[w][tid];
            stg1(parts + (8+tid)*256 + bid, s);
          }
        }
        gsync(wsi, bid, tid, 2*g+2);
        if (wv<4){
          float s=0.f;
          #pragma unroll
          for (int j=0;j<4;++j) s += ldg1(parts + (8+wv)*256 + lane*4+j);
          #pragma unroll
          for (int off=32; off; off>>=1) s += __shfl_xor(s, off);
          if (lane==0) sRed[8+wv]=s;
        }
        __syncthreads();
        #pragma unroll
        for (int c=0;c<4;++c){
          beta[c] = sRed[8+c]/rs[c];
          rs[c]   = sRed[8+c];
        }
        #pragma unroll
        for (int k=0;k<2;++k)
        #pragma unroll
        for (int c=0;c<4;++c) pold[k][c]=pn[k][c];
      } else {
        // ---- last iter: reaction (block-local), publish next b ----
        #pragma unroll
        for (int k=0;k<2;++k){
          float vv[4] = {xx[k][0], xx[k][1], xx[k][2], xx[k][3]};
          float o[4];
          mlp_all(sW, vv, o);
          #pragma unroll
          for (int c=0;c<4;++c) xnew[k][c] = xx[k][c] + DTf*tanhf(o[c]);
        }
        if (step < NSTEPS-1){
          #pragma unroll
          for (int c=0;c<4;++c)
            stg2(ws + R_OFF(c) + grow*NXg + c2,
                 make_float2(gam[c]*xnew[0][c], gam[c]*xnew[1][c]));
          gsync(wsi, bid, tid, 2*g+2);   // folded step-boundary sync
        } else {
          ((float4*)out)[cell0]   = make_float4(xnew[0][0],xnew[0][1],xnew[0][2],xnew[0][3]);
          ((float4*)out)[cell0+1] = make_float4(xnew[1][0],xnew[1][1],xnew[1][2],xnew[1][3]);
        }
      }
    }
  }
}

// diagnostic: runs ONLY if ws is too small — absmax ≈ 54321 signals that.
__global__ void diag_ws(float* out){ out[0] = 54321.0f; }

extern "C" void kernel_launch(void* const* d_in, const int* in_sizes, int n_in,
                              void* d_out, int out_size, void* d_ws, size_t ws_size,
                              hipStream_t stream) {
  const float* U0    = (const float*)d_in[0];
  const float* scale = (const float*)d_in[1];
  const float* K1    = (const float*)d_in[2];
  const float* K2    = (const float*)d_in[3];
  const float* K3    = (const float*)d_in[4];
  float* out = (float*)d_out;
  float* ws  = (float*)d_ws;

  const size_t need = (size_t)(CTRL_FLOATS + 4*NNg) * sizeof(float);
  if (ws_size < need) {
    hipLaunchKernelGGL(diag_ws, dim3(1), dim3(1), 0, stream, out);
    return;
  }
  // zero flags + release lines + parts (harness poisons ws with 0xAA)
  hipMemsetAsync(ws, 0, CTRL_FLOATS*sizeof(float), stream);
  hipLaunchKernelGGL(drk, dim3(NBT), dim3(TPB), 0, stream,
                     U0, scale, K1, K2, K3, out, ws);
}